// Round 17
// baseline (305.072 us; speedup 1.0000x reference)
//
#include <hip/hip_runtime.h>
#include <stdint.h>

#define TT 131072
#define MD 8
#define CHUNK 16
#define RMP 72   // row-major LDS pad (shorts per row)

using f32x4  = __attribute__((ext_vector_type(4))) float;
using bf16x8 = __attribute__((ext_vector_type(8))) __bf16;
using bf16x2 = __attribute__((ext_vector_type(2))) __bf16;
using u32x2  = __attribute__((ext_vector_type(2))) uint32_t;
using u32x4  = __attribute__((ext_vector_type(4))) uint32_t;

// log(n!) for n = 0..19 (x in [0,20))
__device__ __constant__ float c_lg[20] = {
    0.0f, 0.0f, 0.69314718f, 1.79175947f, 3.17805383f,
    4.78749174f, 6.57925121f, 8.52516136f, 10.60460290f, 12.80182748f,
    15.10441257f, 17.50230785f, 19.98721386f, 22.55216385f, 25.19122118f,
    27.89927138f, 30.67186011f, 33.50507345f, 36.39544521f, 39.33988419f};

#define MFMA(a, b, c) __builtin_amdgcn_mfma_f32_16x16x32_bf16((a), (b), (c), 0, 0, 0)

// pack two f32 -> one u32 of 2 bf16 (RNE)
__device__ __forceinline__ uint32_t pk2(float lo, float hi) {
    bf16x2 t = {(__bf16)lo, (__bf16)hi};
    return __builtin_bit_cast(uint32_t, t);
}

// Wave64 max-reduce on the VALU via DPP. Wave-uniform result.
// Used ONLY for rescale factors whose applied value is logged exactly.
__device__ __forceinline__ float wave_max_dpp(float v) {
    int x = __builtin_bit_cast(int, v);
#define DHOP(ctrl)                                                            \
    {                                                                         \
        int y = __builtin_amdgcn_update_dpp(x, x, ctrl, 0xf, 0xf, false);     \
        x = __builtin_bit_cast(int, fmaxf(__builtin_bit_cast(float, x),       \
                                          __builtin_bit_cast(float, y)));     \
    }
    DHOP(0x111)
    DHOP(0x112)
    DHOP(0x114)
    DHOP(0x118)
    DHOP(0x142)
    DHOP(0x143)
#undef DHOP
    return __builtin_bit_cast(float, __builtin_amdgcn_readlane(x, 63));
}

// Bookkeeping fragment map sigma (consistent everywhere; HW map may differ —
// it cancels): frag elem e covers k = 16*(e>>2) + 4*q + (e&3), q = lane>>4;
// A rows / B cols on lane&15. B[kf][nb] holds M[32kf+sigma][16nb+(l&15)].

// full emission (K3 only)
__device__ __forceinline__ void emis(const int4& xa, const int4& xb,
                                     const float* ll, float lamsum,
                                     const float* lgt, float& pe, float& gs) {
    float g = -lamsum;
    g = fmaf((float)xa.x, ll[0], g);
    g = fmaf((float)xa.y, ll[1], g);
    g = fmaf((float)xa.z, ll[2], g);
    g = fmaf((float)xa.w, ll[3], g);
    g = fmaf((float)xb.x, ll[4], g);
    g = fmaf((float)xb.y, ll[5], g);
    g = fmaf((float)xb.z, ll[6], g);
    g = fmaf((float)xb.w, ll[7], g);
    float Lt = lgt[xa.x] + lgt[xa.y] + lgt[xa.z] + lgt[xa.w] +
               lgt[xb.x] + lgt[xb.y] + lgt[xb.z] + lgt[xb.w];
    float gm = wave_max_dpp(g);
    pe = __expf(g - gm);
    gs = gm - Lt;
}

// loop emission: no lgamma (hoisted)
__device__ __forceinline__ void emis_ng(const int4& xa, const int4& xb,
                                        const float* ll, float lamsum,
                                        float& pe, float& gm_out) {
    float g = -lamsum;
    g = fmaf((float)xa.x, ll[0], g);
    g = fmaf((float)xa.y, ll[1], g);
    g = fmaf((float)xa.z, ll[2], g);
    g = fmaf((float)xa.w, ll[3], g);
    g = fmaf((float)xb.x, ll[4], g);
    g = fmaf((float)xb.y, ll[5], g);
    g = fmaf((float)xb.z, ll[6], g);
    g = fmaf((float)xb.w, ll[7], g);
    float gm = wave_max_dpp(g);
    pe = __expf(g - gm);
    gm_out = gm;
}

// ---- fragment <-> memory helpers (map sigma; verified R4) ----

__device__ __forceinline__ void identity_B(bf16x8 B[2][4], int li, int q) {
#pragma unroll
    for (int kf = 0; kf < 2; ++kf)
#pragma unroll
        for (int nb = 0; nb < 4; ++nb) {
            int n = 16 * nb + li;
            u32x4 u;
#pragma unroll
            for (int wi = 0; wi < 4; ++wi) {
                int k0 = 32 * kf + 16 * (wi >> 1) + 4 * q + 2 * (wi & 1);
                uint32_t v = 0;
                if (k0 == n) v |= 0x3F80u;
                if (k0 + 1 == n) v |= 0x3F800000u;
                u[wi] = v;
            }
            B[kf][nb] = __builtin_bit_cast(bf16x8, u);
        }
}

__device__ __forceinline__ void state_to_rm(short* rm, const bf16x8 B[2][4],
                                            int li, int q) {
#pragma unroll
    for (int kf = 0; kf < 2; ++kf)
#pragma unroll
        for (int nb = 0; nb < 4; ++nb) {
            u32x4 u = __builtin_bit_cast(u32x4, B[kf][nb]);
            int n = 16 * nb + li;
#pragma unroll
            for (int wi = 0; wi < 4; ++wi) {
                int k0 = 32 * kf + 16 * (wi >> 1) + 4 * q + 2 * (wi & 1);
                uint32_t v = u[wi];
                rm[k0 * RMP + n] = (short)(v & 0xFFFFu);
                rm[(k0 + 1) * RMP + n] = (short)(v >> 16);
            }
        }
}

__device__ __forceinline__ void dump_rm_g(short* gm, const bf16x8 B[2][4],
                                          int li, int q) {
#pragma unroll
    for (int kf = 0; kf < 2; ++kf)
#pragma unroll
        for (int nb = 0; nb < 4; ++nb) {
            u32x4 u = __builtin_bit_cast(u32x4, B[kf][nb]);
            int n = 16 * nb + li;
#pragma unroll
            for (int wi = 0; wi < 4; ++wi) {
                int k0 = 32 * kf + 16 * (wi >> 1) + 4 * q + 2 * (wi & 1);
                uint32_t v = u[wi];
                gm[k0 * 64 + n] = (short)(v & 0xFFFFu);
                gm[(k0 + 1) * 64 + n] = (short)(v >> 16);
            }
        }
}

__device__ __forceinline__ void load_afrags(const short* rm, int li, int q,
                                            bf16x8 A[4][2]) {
#pragma unroll
    for (int mb = 0; mb < 4; ++mb)
#pragma unroll
        for (int kf = 0; kf < 2; ++kf) {
            const short* p = rm + (16 * mb + li) * RMP + 32 * kf + 4 * q;
            u32x2 lo = *(const u32x2*)p;
            u32x2 hi = *(const u32x2*)(p + 16);
            u32x4 u = {lo[0], lo[1], hi[0], hi[1]};
            A[mb][kf] = __builtin_bit_cast(bf16x8, u);
        }
}

__device__ __forceinline__ void load_afrags_g(const short* gm, int li, int q,
                                              bf16x8 A[4][2]) {
#pragma unroll
    for (int mb = 0; mb < 4; ++mb)
#pragma unroll
        for (int kf = 0; kf < 2; ++kf) {
            const short* p = gm + (16 * mb + li) * 64 + 32 * kf + 4 * q;
            u32x2 lo = *(const u32x2*)p;
            u32x2 hi = *(const u32x2*)(p + 16);
            u32x4 u = {lo[0], lo[1], hi[0], hi[1]};
            A[mb][kf] = __builtin_bit_cast(bf16x8, u);
        }
}

// B <- normalize(A*B); returns applied max. Caller logs it exactly.
__device__ __forceinline__ float leftmul(const bf16x8 A[4][2], bf16x8 B[2][4]) {
    f32x4 d[4][4];
#pragma unroll
    for (int mb = 0; mb < 4; ++mb)
#pragma unroll
        for (int nb = 0; nb < 4; ++nb) {
            f32x4 z = {0.f, 0.f, 0.f, 0.f};
            d[mb][nb] = MFMA(A[mb][0], B[0][nb], z);
            d[mb][nb] = MFMA(A[mb][1], B[1][nb], d[mb][nb]);
        }
    float pm = 0.f;
#pragma unroll
    for (int mb = 0; mb < 4; ++mb)
#pragma unroll
        for (int nb = 0; nb < 4; ++nb)
            pm = fmaxf(pm, fmaxf(fmaxf(d[mb][nb][0], d[mb][nb][1]),
                                 fmaxf(d[mb][nb][2], d[mb][nb][3])));
    pm = wave_max_dpp(pm);
    pm = fmaxf(pm, 1e-30f);
    float r = 1.0f / pm;
#pragma unroll
    for (int mb = 0; mb < 4; ++mb)
#pragma unroll
        for (int nb = 0; nb < 4; ++nb) {
#pragma unroll
            for (int reg = 0; reg < 4; ++reg)
                B[mb >> 1][nb][(mb & 1) * 4 + reg] =
                    (__bf16)(d[mb][nb][reg] * r);
        }
    return pm;
}

// Depth-2 pipelined step (R16-verified math). pes/xs live in LDS aliased onto
// rm (main-loop lifetime only). EVEN: rescale by NRM (2-lag, exact f64 log).
#define STEPE(BIN, BOUT, NRM, GSC, GSN, SACC, CHI)                           \
    {                                                                        \
        int sl_ = s + 2 > CHUNK - 1 ? CHUNK - 1 : s + 2;                     \
        int4 xa_ = xw[CHI * 32 + 2 * sl_];                                   \
        int4 xb_ = xw[CHI * 32 + 2 * sl_ + 1];                               \
        float pen_, gmn_;                                                    \
        emis_ng(xa_, xb_, ll, lamsum, pen_, gmn_);                           \
        GSN = gmn_;                                                          \
        pesf[(((s + 2) & 3) * 8 + CHI * 4 + w) * 64 + l] = pen_;             \
        float r_ = 1.0f / NRM;                                               \
        SACC += (double)GSC + (double)__logf(NRM);                           \
        const float* pc_ = pesf + ((s & 3) * 8 + CHI * 4 + w) * 64;          \
        f32x4 scv0 = *(const f32x4*)(pc_ + 4 * q) * r_;                      \
        f32x4 scv1 = *(const f32x4*)(pc_ + 16 + 4 * q) * r_;                 \
        f32x4 scv2 = *(const f32x4*)(pc_ + 32 + 4 * q) * r_;                 \
        f32x4 scv3 = *(const f32x4*)(pc_ + 48 + 4 * q) * r_;                 \
        f32x4 mx_ = {0.f, 0.f, 0.f, 0.f};                                    \
        _Pragma("unroll") for (int nb = 0; nb < 4; ++nb) {                   \
            f32x4 z = {0.f, 0.f, 0.f, 0.f};                                  \
            f32x4 d0 = MFMA(TA[0][0], BIN[0][nb], z);                        \
            d0 = MFMA(TA[0][1], BIN[1][nb], d0);                             \
            f32x4 d1 = MFMA(TA[1][0], BIN[0][nb], z);                        \
            d1 = MFMA(TA[1][1], BIN[1][nb], d1);                             \
            d0 *= scv0;                                                      \
            d1 *= scv1;                                                      \
            mx_ = __builtin_elementwise_max(mx_, d0);                        \
            mx_ = __builtin_elementwise_max(mx_, d1);                        \
            u32x4 u0 = {pk2(d0[0], d0[1]), pk2(d0[2], d0[3]),                \
                        pk2(d1[0], d1[1]), pk2(d1[2], d1[3])};               \
            BOUT[0][nb] = __builtin_bit_cast(bf16x8, u0);                    \
            f32x4 d2 = MFMA(TA[2][0], BIN[0][nb], z);                        \
            d2 = MFMA(TA[2][1], BIN[1][nb], d2);                             \
            f32x4 d3 = MFMA(TA[3][0], BIN[0][nb], z);                        \
            d3 = MFMA(TA[3][1], BIN[1][nb], d3);                             \
            d2 *= scv2;                                                      \
            d3 *= scv3;                                                      \
            mx_ = __builtin_elementwise_max(mx_, d2);                        \
            mx_ = __builtin_elementwise_max(mx_, d3);                        \
            u32x4 u1 = {pk2(d2[0], d2[1]), pk2(d2[2], d2[3]),                \
                        pk2(d3[0], d3[1]), pk2(d3[2], d3[3])};               \
            BOUT[1][nb] = __builtin_bit_cast(bf16x8, u1);                    \
        }                                                                    \
        float pm_ = fmaxf(fmaxf(mx_[0], mx_[1]), fmaxf(mx_[2], mx_[3]));     \
        pm_ = wave_max_dpp(pm_);                                             \
        NRM = fmaxf(pm_, 1e-30f);                                            \
    }

// ODD step: no rescale (r=1), no max tracking.
#define STEPO(BIN, BOUT, GSC, GSN, SACC, CHI)                                \
    {                                                                        \
        int sl_ = s + 2 > CHUNK - 1 ? CHUNK - 1 : s + 2;                     \
        int4 xa_ = xw[CHI * 32 + 2 * sl_];                                   \
        int4 xb_ = xw[CHI * 32 + 2 * sl_ + 1];                               \
        float pen_, gmn_;                                                    \
        emis_ng(xa_, xb_, ll, lamsum, pen_, gmn_);                           \
        GSN = gmn_;                                                          \
        pesf[(((s + 2) & 3) * 8 + CHI * 4 + w) * 64 + l] = pen_;             \
        SACC += (double)GSC;                                                 \
        const float* pc_ = pesf + ((s & 3) * 8 + CHI * 4 + w) * 64;          \
        f32x4 scv0 = *(const f32x4*)(pc_ + 4 * q);                           \
        f32x4 scv1 = *(const f32x4*)(pc_ + 16 + 4 * q);                      \
        f32x4 scv2 = *(const f32x4*)(pc_ + 32 + 4 * q);                      \
        f32x4 scv3 = *(const f32x4*)(pc_ + 48 + 4 * q);                      \
        _Pragma("unroll") for (int nb = 0; nb < 4; ++nb) {                   \
            f32x4 z = {0.f, 0.f, 0.f, 0.f};                                  \
            f32x4 d0 = MFMA(TA[0][0], BIN[0][nb], z);                        \
            d0 = MFMA(TA[0][1], BIN[1][nb], d0);                             \
            f32x4 d1 = MFMA(TA[1][0], BIN[0][nb], z);                        \
            d1 = MFMA(TA[1][1], BIN[1][nb], d1);                             \
            d0 *= scv0;                                                      \
            d1 *= scv1;                                                      \
            u32x4 u0 = {pk2(d0[0], d0[1]), pk2(d0[2], d0[3]),                \
                        pk2(d1[0], d1[1]), pk2(d1[2], d1[3])};               \
            BOUT[0][nb] = __builtin_bit_cast(bf16x8, u0);                    \
            f32x4 d2 = MFMA(TA[2][0], BIN[0][nb], z);                        \
            d2 = MFMA(TA[2][1], BIN[1][nb], d2);                             \
            f32x4 d3 = MFMA(TA[3][0], BIN[0][nb], z);                        \
            d3 = MFMA(TA[3][1], BIN[1][nb], d3);                             \
            d2 *= scv2;                                                      \
            d3 *= scv3;                                                      \
            u32x4 u1 = {pk2(d2[0], d2[1]), pk2(d2[2], d2[3]),                \
                        pk2(d3[0], d3[1]), pk2(d3[2], d3[3])};               \
            BOUT[1][nb] = __builtin_bit_cast(bf16x8, u1);                    \
        }                                                                    \
    }

// ---------------- K1: 2 chunks/wave, CHUNK=16, 4 blocks/CU ------------------
// LDS ~37KB: pes (8KB) + xs (4KB) aliased onto rm (36.8KB, epilogue-only).
__global__ __launch_bounds__(256, 4) void k_chunks(
    const int* __restrict__ x, const float* __restrict__ lambdas,
    const float* __restrict__ logT, short* __restrict__ M1,
    double* __restrict__ S1) {
    __shared__ short rm[4][64 * RMP];
    __shared__ float lgt[20];
    __shared__ double Sw[4];
    float* const pesf = (float*)&rm[0][0];                   // 2048 f = 8KB
    int4* const xsb = (int4*)((char*)&rm[0][0] + 8192);      // 256 int4 = 4KB
    const int tid = threadIdx.x;
    const int l = tid & 63, w = tid >> 6;
    const int li = l & 15, q = l >> 4;
    const int4* const xw = xsb + w * 64;
    if (tid < 20) lgt[tid] = c_lg[tid];

    const int c0 = (blockIdx.x * 4 + w) * 2;
    const int t0a = 1 + c0 * CHUNK;
    const int t0b = t0a + CHUNK;
    const int lenB = min(CHUNK, TT - t0b);

    // stage 32 x rows (1KB/wave) coalesced: lane l -> xs[w][l] (= row l>>1)
    {
        int r0 = l >> 1, h = l & 1;
        int tr = t0a + r0;
        tr = tr > TT - 1 ? TT - 1 : tr;
        xsb[w * 64 + l] = *(const int4*)(x + (size_t)tr * MD + h * 4);
    }

    float ll[8];
    float lamsum = 0.f;
#pragma unroll
    for (int m = 0; m < 8; ++m) {
        float lam = lambdas[l * 8 + m];
        ll[m] = __logf(lam);
        lamsum += lam;
    }

    // constant A-frags of T (shared by both chunks)
    bf16x8 TA[4][2];
#pragma unroll
    for (int mb = 0; mb < 4; ++mb)
#pragma unroll
        for (int kf = 0; kf < 2; ++kf) {
            const float* tp = logT + (16 * mb + li) * 64 + 32 * kf + 4 * q;
            float4 v0 = *(const float4*)tp;
            float4 v1 = *(const float4*)(tp + 16);
            bf16x8 a;
            a[0] = (__bf16)__expf(v0.x);
            a[1] = (__bf16)__expf(v0.y);
            a[2] = (__bf16)__expf(v0.z);
            a[3] = (__bf16)__expf(v0.w);
            a[4] = (__bf16)__expf(v1.x);
            a[5] = (__bf16)__expf(v1.y);
            a[6] = (__bf16)__expf(v1.z);
            a[7] = (__bf16)__expf(v1.w);
            TA[mb][kf] = a;
        }

    bf16x8 B0a[2][4], B1a[2][4], B0b[2][4], B1b[2][4];
    identity_B(B0a, li, q);
    identity_B(B0b, li, q);
    __syncthreads();  // lgt + xs visible

    double Sa = 0.0, Sb = 0.0;
    float nA_a = 1.0f, nA_b = 1.0f;      // 2-lag nrm (even steps)
    float gE0a, gE1a, gO0a, gO1a;        // gs rings (even/odd, 2-deep)
    float gE0b, gE1b, gO0b, gO1b;
    {
        float pe_;
        emis_ng(xw[0], xw[1], ll, lamsum, pe_, gE0a);
        pesf[(0 * 8 + 0 * 4 + w) * 64 + l] = pe_;
        emis_ng(xw[2], xw[3], ll, lamsum, pe_, gO0a);
        pesf[(1 * 8 + 0 * 4 + w) * 64 + l] = pe_;
        emis_ng(xw[32], xw[33], ll, lamsum, pe_, gE0b);
        pesf[(0 * 8 + 1 * 4 + w) * 64 + l] = pe_;
        emis_ng(xw[34], xw[35], ll, lamsum, pe_, gO0b);
        pesf[(1 * 8 + 1 * 4 + w) * 64 + l] = pe_;
    }

    int s = 0;
#pragma unroll 1
    for (int p = 0; p < 3; ++p) {  // 12 steps
        STEPE(B0a, B1a, nA_a, gE0a, gE1a, Sa, 0);
        STEPE(B0b, B1b, nA_b, gE0b, gE1b, Sb, 1);
        ++s;
        STEPO(B1a, B0a, gO0a, gO1a, Sa, 0);
        STEPO(B1b, B0b, gO0b, gO1b, Sb, 1);
        ++s;
        STEPE(B0a, B1a, nA_a, gE1a, gE0a, Sa, 0);
        STEPE(B0b, B1b, nA_b, gE1b, gE0b, Sb, 1);
        ++s;
        STEPO(B1a, B0a, gO1a, gO0a, Sa, 0);
        STEPO(B1b, B0b, gO1b, gO0b, Sb, 1);
        ++s;
    }
    // tail: steps 12..15
    STEPE(B0a, B1a, nA_a, gE0a, gE1a, Sa, 0);
    STEPE(B0b, B1b, nA_b, gE0b, gE1b, Sb, 1);
    ++s;
    STEPO(B1a, B0a, gO0a, gO1a, Sa, 0);
    STEPO(B1b, B0b, gO0b, gO1b, Sb, 1);
    ++s;
    STEPE(B0a, B1a, nA_a, gE1a, gE0a, Sa, 0);
    STEPE(B0b, B1b, nA_b, gE1b, gE0b, Sb, 1);
    ++s;
    STEPO(B1a, B0a, gO1a, gO0a, Sa, 0);
    if (lenB == CHUNK) {
        STEPO(B1b, B0b, gO1b, gO0b, Sb, 1);
    } else {
#pragma unroll
        for (int kf = 0; kf < 2; ++kf)
#pragma unroll
            for (int nb = 0; nb < 4; ++nb) B0b[kf][nb] = B1b[kf][nb];
    }

    // hoisted lgamma over both chunks (32 staged rows, from LDS)
    {
        const int lenTot = CHUNK + lenB;
        float lt = 0.f;
        if (l < lenTot) {
            int4 a = xw[2 * l], b = xw[2 * l + 1];
            lt = lgt[a.x] + lgt[a.y] + lgt[a.z] + lgt[a.w] + lgt[b.x] +
                 lgt[b.y] + lgt[b.z] + lgt[b.w];
        }
#pragma unroll
        for (int m = 1; m <= 32; m <<= 1) lt += __shfl_xor(lt, m, 64);
        Sa -= (double)lt;
    }
    __syncthreads();  // pes/xs lifetimes end; rm region reusable

    // ---- intra-wave pair product: Mpair = M_B * M_A ----
    state_to_rm(&rm[w][0], B0b, li, q);
    {
        bf16x8 Ap[4][2];
        load_afrags(&rm[w][0], li, q, Ap);
        float pm = leftmul(Ap, B0a);
        Sa += Sb + (double)__logf(pm);
    }

    // ---- cross-wave combine: product = P3*P2*P1*P0 ----
    __syncthreads();
    if (w) state_to_rm(&rm[w][0], B0a, li, q);
    if (l == 0) Sw[w] = Sa;
    __syncthreads();
    if (w == 0) {
        double S = Sa;
#pragma unroll 1
        for (int j = 1; j < 4; ++j) {
            bf16x8 A[4][2];
            load_afrags(&rm[j][0], li, q, A);
            float pm = leftmul(A, B0a);
            S += Sw[j] + (double)__logf(pm);
        }
        dump_rm_g(M1 + (size_t)blockIdx.x * 4096, B0a, li, q);
        if (l == 0) S1[blockIdx.x] = S;
    }
}

// ---------------- K2: fold 1024 -> 64 ----------------------------------------
__global__ __launch_bounds__(256, 1) void k_combine(
    const short* __restrict__ M1, const double* __restrict__ S1,
    short* __restrict__ M2, double* __restrict__ S2) {
    __shared__ short rm[4][64 * RMP];
    __shared__ double Sw[4];
    const int tid = threadIdx.x;
    const int l = tid & 63, w = tid >> 6;
    const int li = l & 15, q = l >> 4;
    const int base = (blockIdx.x * 4 + w) * 4;

    bf16x8 B[2][4];
    identity_B(B, li, q);
    double S = 0.0;
    bf16x8 Aa[4][2], Ab[4][2];
    load_afrags_g(M1 + (size_t)base * 4096, li, q, Aa);
    load_afrags_g(M1 + (size_t)(base + 1) * 4096, li, q, Ab);
    float pm = leftmul(Aa, B);
    S += S1[base] + (double)__logf(pm);
    load_afrags_g(M1 + (size_t)(base + 2) * 4096, li, q, Aa);
    pm = leftmul(Ab, B);
    S += S1[base + 1] + (double)__logf(pm);
    load_afrags_g(M1 + (size_t)(base + 3) * 4096, li, q, Ab);
    pm = leftmul(Aa, B);
    S += S1[base + 2] + (double)__logf(pm);
    pm = leftmul(Ab, B);
    S += S1[base + 3] + (double)__logf(pm);

    if (w) state_to_rm(&rm[w][0], B, li, q);
    if (l == 0) Sw[w] = S;
    __syncthreads();
    if (w == 0) {
#pragma unroll 1
        for (int j = 1; j < 4; ++j) {
            bf16x8 A[4][2];
            load_afrags(&rm[j][0], li, q, A);
            float pmj = leftmul(A, B);
            S += Sw[j] + (double)__logf(pmj);
        }
        dump_rm_g(M2 + (size_t)blockIdx.x * 4096, B, li, q);
        if (l == 0) S2[blockIdx.x] = S;
    }
}

// ---------------- K3: fold 64 -> 1, alpha0, final LSE ------------------------
__global__ __launch_bounds__(256, 1) void k_final(
    const int* __restrict__ x, const float* __restrict__ lambdas,
    const float* __restrict__ prior, const short* __restrict__ M2,
    const double* __restrict__ S2, float* __restrict__ out) {
    __shared__ short rm[4][64 * RMP];
    __shared__ double Sw[4];
    __shared__ float lgt[20];
    const int tid = threadIdx.x;
    const int l = tid & 63, w = tid >> 6;
    const int li = l & 15, q = l >> 4;
    if (tid < 20) lgt[tid] = c_lg[tid];
    __syncthreads();

    const int base = w * 16;
    bf16x8 B[2][4];
    identity_B(B, li, q);
    double S = 0.0;
    bf16x8 Aa[4][2], Ab[4][2];
    load_afrags_g(M2 + (size_t)base * 4096, li, q, Aa);
#pragma unroll
    for (int j = 0; j < 16; j += 2) {
        load_afrags_g(M2 + (size_t)(base + j + 1) * 4096, li, q, Ab);
        float pm = leftmul(Aa, B);
        S += S2[base + j] + (double)__logf(pm);
        if (j + 2 < 16)
            load_afrags_g(M2 + (size_t)(base + j + 2) * 4096, li, q, Aa);
        pm = leftmul(Ab, B);
        S += S2[base + j + 1] + (double)__logf(pm);
    }

    if (w) state_to_rm(&rm[w][0], B, li, q);
    if (l == 0) Sw[w] = S;
    __syncthreads();
    if (w == 0) {
#pragma unroll 1
        for (int j = 1; j < 4; ++j) {
            bf16x8 A[4][2];
            load_afrags(&rm[j][0], li, q, A);
            float pm = leftmul(A, B);
            S += Sw[j] + (double)__logf(pm);
        }
        // finalize: alpha0 = em_0 * exp(prior); total = 1^T B alpha0
        float ll[8];
        float lamsum = 0.f;
#pragma unroll
        for (int m = 0; m < 8; ++m) {
            float lam = lambdas[l * 8 + m];
            ll[m] = __logf(lam);
            lamsum += lam;
        }
        int4 xa = *(const int4*)(x);
        int4 xb = *(const int4*)(x + 4);
        float pe0, gs0;
        emis(xa, xb, ll, lamsum, lgt, pe0, gs0);
        S += (double)gs0;
        float a0 = pe0 * __expf(prior[l]);

        float av[4];
#pragma unroll
        for (int nb = 0; nb < 4; ++nb) av[nb] = __shfl(a0, 16 * nb + li, 64);

        float acc = 0.f;
#pragma unroll
        for (int kf = 0; kf < 2; ++kf)
#pragma unroll
            for (int nb = 0; nb < 4; ++nb) {
                u32x4 u = __builtin_bit_cast(u32x4, B[kf][nb]);
#pragma unroll
                for (int e = 0; e < 4; ++e) {
                    float flo = __builtin_bit_cast(float, u[e] << 16);
                    float fhi = __builtin_bit_cast(float, u[e] & 0xFFFF0000u);
                    acc = fmaf(flo + fhi, av[nb], acc);
                }
            }
#pragma unroll
        for (int m = 1; m <= 32; m <<= 1) acc += __shfl_xor(acc, m, 64);
        if (l == 0) out[0] = (float)(S + (double)__logf(acc));
    }
}

extern "C" void kernel_launch(void* const* d_in, const int* in_sizes, int n_in,
                              void* d_out, int out_size, void* d_ws,
                              size_t ws_size, hipStream_t stream) {
    const int* x = (const int*)d_in[0];
    const float* lambdas = (const float*)d_in[1];
    const float* logT = (const float*)d_in[2];
    const float* prior = (const float*)d_in[3];
    float* out = (float*)d_out;
    char* ws = (char*)d_ws;
    // ws layout (~8.92 MB): M1 1024*8KB, S1 1024*8B, M2 64*8KB, S2 64*8B
    short* M1 = (short*)ws;
    double* S1 = (double*)(ws + 8388608);
    short* M2 = (short*)(ws + 8396800);
    double* S2 = (double*)(ws + 8921088);

    k_chunks<<<1024, 256, 0, stream>>>(x, lambdas, logT, M1, S1);
    k_combine<<<64, 256, 0, stream>>>(M1, S1, M2, S2);
    k_final<<<1, 256, 0, stream>>>(x, lambdas, prior, M2, S2, out);
}

// Round 18
// 113.554 us; speedup vs baseline: 2.6866x; 2.6866x over previous
//
#include <hip/hip_runtime.h>
#include <stdint.h>

#define TT 131072
#define MD 8
#define CHUNK 32
#define RMP 72   // row-major LDS pad (shorts per row)

using f32x4  = __attribute__((ext_vector_type(4))) float;
using bf16x8 = __attribute__((ext_vector_type(8))) __bf16;
using bf16x2 = __attribute__((ext_vector_type(2))) __bf16;
using u32x2  = __attribute__((ext_vector_type(2))) uint32_t;
using u32x4  = __attribute__((ext_vector_type(4))) uint32_t;

// log(n!) for n = 0..19 (x in [0,20))
__device__ __constant__ float c_lg[20] = {
    0.0f, 0.0f, 0.69314718f, 1.79175947f, 3.17805383f,
    4.78749174f, 6.57925121f, 8.52516136f, 10.60460290f, 12.80182748f,
    15.10441257f, 17.50230785f, 19.98721386f, 22.55216385f, 25.19122118f,
    27.89927138f, 30.67186011f, 33.50507345f, 36.39544521f, 39.33988419f};

#define MFMA(a, b, c) __builtin_amdgcn_mfma_f32_16x16x32_bf16((a), (b), (c), 0, 0, 0)

// pack two f32 -> one u32 of 2 bf16 (RNE)
__device__ __forceinline__ uint32_t pk2(float lo, float hi) {
    bf16x2 t = {(__bf16)lo, (__bf16)hi};
    return __builtin_bit_cast(uint32_t, t);
}

// Wave64 max-reduce on the VALU via DPP. Wave-uniform result.
// Used ONLY for rescale factors whose applied value is logged exactly.
__device__ __forceinline__ float wave_max_dpp(float v) {
    int x = __builtin_bit_cast(int, v);
#define DHOP(ctrl)                                                            \
    {                                                                         \
        int y = __builtin_amdgcn_update_dpp(x, x, ctrl, 0xf, 0xf, false);     \
        x = __builtin_bit_cast(int, fmaxf(__builtin_bit_cast(float, x),       \
                                          __builtin_bit_cast(float, y)));     \
    }
    DHOP(0x111)
    DHOP(0x112)
    DHOP(0x114)
    DHOP(0x118)
    DHOP(0x142)
    DHOP(0x143)
#undef DHOP
    return __builtin_bit_cast(float, __builtin_amdgcn_readlane(x, 63));
}

// Bookkeeping fragment map sigma (consistent everywhere; HW map may differ —
// it cancels): frag elem e covers k = 16*(e>>2) + 4*q + (e&3), q = lane>>4;
// A rows / B cols on lane&15. B[kf][nb] holds M[32kf+sigma][16nb+(l&15)].

// full emission (K3 only)
__device__ __forceinline__ void emis(const int4& xa, const int4& xb,
                                     const float* ll, float lamsum,
                                     const float* lgt, float& pe, float& gs) {
    float g = -lamsum;
    g = fmaf((float)xa.x, ll[0], g);
    g = fmaf((float)xa.y, ll[1], g);
    g = fmaf((float)xa.z, ll[2], g);
    g = fmaf((float)xa.w, ll[3], g);
    g = fmaf((float)xb.x, ll[4], g);
    g = fmaf((float)xb.y, ll[5], g);
    g = fmaf((float)xb.z, ll[6], g);
    g = fmaf((float)xb.w, ll[7], g);
    float Lt = lgt[xa.x] + lgt[xa.y] + lgt[xa.z] + lgt[xa.w] +
               lgt[xb.x] + lgt[xb.y] + lgt[xb.z] + lgt[xb.w];
    float gm = wave_max_dpp(g);
    pe = __expf(g - gm);
    gs = gm - Lt;
}

// loop emission: no lgamma (hoisted)
__device__ __forceinline__ void emis_ng(const int4& xa, const int4& xb,
                                        const float* ll, float lamsum,
                                        float& pe, float& gm_out) {
    float g = -lamsum;
    g = fmaf((float)xa.x, ll[0], g);
    g = fmaf((float)xa.y, ll[1], g);
    g = fmaf((float)xa.z, ll[2], g);
    g = fmaf((float)xa.w, ll[3], g);
    g = fmaf((float)xb.x, ll[4], g);
    g = fmaf((float)xb.y, ll[5], g);
    g = fmaf((float)xb.z, ll[6], g);
    g = fmaf((float)xb.w, ll[7], g);
    float gm = wave_max_dpp(g);
    pe = __expf(g - gm);
    gm_out = gm;
}

// ---- fragment <-> memory helpers (map sigma; verified R4) ----

__device__ __forceinline__ void identity_B(bf16x8 B[2][4], int li, int q) {
#pragma unroll
    for (int kf = 0; kf < 2; ++kf)
#pragma unroll
        for (int nb = 0; nb < 4; ++nb) {
            int n = 16 * nb + li;
            u32x4 u;
#pragma unroll
            for (int wi = 0; wi < 4; ++wi) {
                int k0 = 32 * kf + 16 * (wi >> 1) + 4 * q + 2 * (wi & 1);
                uint32_t v = 0;
                if (k0 == n) v |= 0x3F80u;
                if (k0 + 1 == n) v |= 0x3F800000u;
                u[wi] = v;
            }
            B[kf][nb] = __builtin_bit_cast(bf16x8, u);
        }
}

__device__ __forceinline__ void state_to_rm(short* rm, const bf16x8 B[2][4],
                                            int li, int q) {
#pragma unroll
    for (int kf = 0; kf < 2; ++kf)
#pragma unroll
        for (int nb = 0; nb < 4; ++nb) {
            u32x4 u = __builtin_bit_cast(u32x4, B[kf][nb]);
            int n = 16 * nb + li;
#pragma unroll
            for (int wi = 0; wi < 4; ++wi) {
                int k0 = 32 * kf + 16 * (wi >> 1) + 4 * q + 2 * (wi & 1);
                uint32_t v = u[wi];
                rm[k0 * RMP + n] = (short)(v & 0xFFFFu);
                rm[(k0 + 1) * RMP + n] = (short)(v >> 16);
            }
        }
}

__device__ __forceinline__ void dump_rm_g(short* gm, const bf16x8 B[2][4],
                                          int li, int q) {
#pragma unroll
    for (int kf = 0; kf < 2; ++kf)
#pragma unroll
        for (int nb = 0; nb < 4; ++nb) {
            u32x4 u = __builtin_bit_cast(u32x4, B[kf][nb]);
            int n = 16 * nb + li;
#pragma unroll
            for (int wi = 0; wi < 4; ++wi) {
                int k0 = 32 * kf + 16 * (wi >> 1) + 4 * q + 2 * (wi & 1);
                uint32_t v = u[wi];
                gm[k0 * 64 + n] = (short)(v & 0xFFFFu);
                gm[(k0 + 1) * 64 + n] = (short)(v >> 16);
            }
        }
}

__device__ __forceinline__ void load_afrags(const short* rm, int li, int q,
                                            bf16x8 A[4][2]) {
#pragma unroll
    for (int mb = 0; mb < 4; ++mb)
#pragma unroll
        for (int kf = 0; kf < 2; ++kf) {
            const short* p = rm + (16 * mb + li) * RMP + 32 * kf + 4 * q;
            u32x2 lo = *(const u32x2*)p;
            u32x2 hi = *(const u32x2*)(p + 16);
            u32x4 u = {lo[0], lo[1], hi[0], hi[1]};
            A[mb][kf] = __builtin_bit_cast(bf16x8, u);
        }
}

__device__ __forceinline__ void load_afrags_g(const short* gm, int li, int q,
                                              bf16x8 A[4][2]) {
#pragma unroll
    for (int mb = 0; mb < 4; ++mb)
#pragma unroll
        for (int kf = 0; kf < 2; ++kf) {
            const short* p = gm + (16 * mb + li) * 64 + 32 * kf + 4 * q;
            u32x2 lo = *(const u32x2*)p;
            u32x2 hi = *(const u32x2*)(p + 16);
            u32x4 u = {lo[0], lo[1], hi[0], hi[1]};
            A[mb][kf] = __builtin_bit_cast(bf16x8, u);
        }
}

// B <- normalize(A*B); returns applied max. Caller logs it exactly.
__device__ __forceinline__ float leftmul(const bf16x8 A[4][2], bf16x8 B[2][4]) {
    f32x4 d[4][4];
#pragma unroll
    for (int mb = 0; mb < 4; ++mb)
#pragma unroll
        for (int nb = 0; nb < 4; ++nb) {
            f32x4 z = {0.f, 0.f, 0.f, 0.f};
            d[mb][nb] = MFMA(A[mb][0], B[0][nb], z);
            d[mb][nb] = MFMA(A[mb][1], B[1][nb], d[mb][nb]);
        }
    float pm = 0.f;
#pragma unroll
    for (int mb = 0; mb < 4; ++mb)
#pragma unroll
        for (int nb = 0; nb < 4; ++nb)
            pm = fmaxf(pm, fmaxf(fmaxf(d[mb][nb][0], d[mb][nb][1]),
                                 fmaxf(d[mb][nb][2], d[mb][nb][3])));
    pm = wave_max_dpp(pm);
    pm = fmaxf(pm, 1e-30f);
    float r = 1.0f / pm;
#pragma unroll
    for (int mb = 0; mb < 4; ++mb)
#pragma unroll
        for (int nb = 0; nb < 4; ++nb) {
#pragma unroll
            for (int reg = 0; reg < 4; ++reg)
                B[mb >> 1][nb][(mb & 1) * 4 + reg] =
                    (__bf16)(d[mb][nb][reg] * r);
        }
    return pm;
}

// Half-step MFMA batch: rows {2G, 2G+1} x all 4 col-blocks.
// Phase 1: 8 INDEPENDENT MFMAs (kf=0, zero-init); phase 2: 8 dependents
// (kf=1) — maximizes in-flight MFMA chains (R16 had only ~2).
#define MFMA_GROUP(BIN, G, E)                                                \
    {                                                                        \
        f32x4 z = {0.f, 0.f, 0.f, 0.f};                                      \
        _Pragma("unroll") for (int nb = 0; nb < 4; ++nb) {                   \
            E[2 * nb] = MFMA(TA[2 * G][0], BIN[0][nb], z);                   \
            E[2 * nb + 1] = MFMA(TA[2 * G + 1][0], BIN[0][nb], z);           \
        }                                                                    \
        _Pragma("unroll") for (int nb = 0; nb < 4; ++nb) {                   \
            E[2 * nb] = MFMA(TA[2 * G][1], BIN[1][nb], E[2 * nb]);           \
            E[2 * nb + 1] = MFMA(TA[2 * G + 1][1], BIN[1][nb], E[2 * nb + 1]); \
        }                                                                    \
    }

// Depth-2 pipelined step (R16-verified math; MFMA-batched schedule).
// EVEN: rescale by NRM (2-lag, exact f64 log), track new max.
#define STEPE(BIN, BOUT, NRM, GSC, GSN, SACC, CHI)                           \
    {                                                                        \
        int sl_ = s + 2 > CHUNK - 1 ? CHUNK - 1 : s + 2;                     \
        int4 xa_ = xs[w][CHI * 64 + 2 * sl_];                                \
        int4 xb_ = xs[w][CHI * 64 + 2 * sl_ + 1];                            \
        float pen_, gmn_;                                                    \
        emis_ng(xa_, xb_, ll, lamsum, pen_, gmn_);                           \
        GSN = gmn_;                                                          \
        pes[(s + 2) & 3][CHI][w][l] = pen_;                                  \
        float r_ = 1.0f / NRM;                                               \
        SACC += (double)GSC + (double)__logf(NRM);                           \
        const float* pc_ = &pes[s & 3][CHI][w][0];                           \
        f32x4 scv0 = *(const f32x4*)(pc_ + 4 * q) * r_;                      \
        f32x4 scv1 = *(const f32x4*)(pc_ + 16 + 4 * q) * r_;                 \
        f32x4 scv2 = *(const f32x4*)(pc_ + 32 + 4 * q) * r_;                 \
        f32x4 scv3 = *(const f32x4*)(pc_ + 48 + 4 * q) * r_;                 \
        f32x4 mx_ = {0.f, 0.f, 0.f, 0.f};                                    \
        f32x4 e[8];                                                          \
        MFMA_GROUP(BIN, 0, e);                                               \
        _Pragma("unroll") for (int nb = 0; nb < 4; ++nb) {                   \
            f32x4 d0 = e[2 * nb] * scv0;                                     \
            f32x4 d1 = e[2 * nb + 1] * scv1;                                 \
            mx_ = __builtin_elementwise_max(mx_, d0);                        \
            mx_ = __builtin_elementwise_max(mx_, d1);                        \
            u32x4 u0 = {pk2(d0[0], d0[1]), pk2(d0[2], d0[3]),                \
                        pk2(d1[0], d1[1]), pk2(d1[2], d1[3])};               \
            BOUT[0][nb] = __builtin_bit_cast(bf16x8, u0);                    \
        }                                                                    \
        MFMA_GROUP(BIN, 1, e);                                               \
        _Pragma("unroll") for (int nb = 0; nb < 4; ++nb) {                   \
            f32x4 d2 = e[2 * nb] * scv2;                                     \
            f32x4 d3 = e[2 * nb + 1] * scv3;                                 \
            mx_ = __builtin_elementwise_max(mx_, d2);                        \
            mx_ = __builtin_elementwise_max(mx_, d3);                        \
            u32x4 u1 = {pk2(d2[0], d2[1]), pk2(d2[2], d2[3]),                \
                        pk2(d3[0], d3[1]), pk2(d3[2], d3[3])};               \
            BOUT[1][nb] = __builtin_bit_cast(bf16x8, u1);                    \
        }                                                                    \
        float pm_ = fmaxf(fmaxf(mx_[0], mx_[1]), fmaxf(mx_[2], mx_[3]));     \
        pm_ = wave_max_dpp(pm_);                                             \
        NRM = fmaxf(pm_, 1e-30f);                                            \
    }

// ODD step: no rescale (r=1), no max tracking.
#define STEPO(BIN, BOUT, GSC, GSN, SACC, CHI)                                \
    {                                                                        \
        int sl_ = s + 2 > CHUNK - 1 ? CHUNK - 1 : s + 2;                     \
        int4 xa_ = xs[w][CHI * 64 + 2 * sl_];                                \
        int4 xb_ = xs[w][CHI * 64 + 2 * sl_ + 1];                            \
        float pen_, gmn_;                                                    \
        emis_ng(xa_, xb_, ll, lamsum, pen_, gmn_);                           \
        GSN = gmn_;                                                          \
        pes[(s + 2) & 3][CHI][w][l] = pen_;                                  \
        SACC += (double)GSC;                                                 \
        const float* pc_ = &pes[s & 3][CHI][w][0];                           \
        f32x4 scv0 = *(const f32x4*)(pc_ + 4 * q);                           \
        f32x4 scv1 = *(const f32x4*)(pc_ + 16 + 4 * q);                      \
        f32x4 scv2 = *(const f32x4*)(pc_ + 32 + 4 * q);                      \
        f32x4 scv3 = *(const f32x4*)(pc_ + 48 + 4 * q);                      \
        f32x4 e[8];                                                          \
        MFMA_GROUP(BIN, 0, e);                                               \
        _Pragma("unroll") for (int nb = 0; nb < 4; ++nb) {                   \
            f32x4 d0 = e[2 * nb] * scv0;                                     \
            f32x4 d1 = e[2 * nb + 1] * scv1;                                 \
            u32x4 u0 = {pk2(d0[0], d0[1]), pk2(d0[2], d0[3]),                \
                        pk2(d1[0], d1[1]), pk2(d1[2], d1[3])};               \
            BOUT[0][nb] = __builtin_bit_cast(bf16x8, u0);                    \
        }                                                                    \
        MFMA_GROUP(BIN, 1, e);                                               \
        _Pragma("unroll") for (int nb = 0; nb < 4; ++nb) {                   \
            f32x4 d2 = e[2 * nb] * scv2;                                     \
            f32x4 d3 = e[2 * nb + 1] * scv3;                                 \
            u32x4 u1 = {pk2(d2[0], d2[1]), pk2(d2[2], d2[3]),                \
                        pk2(d3[0], d3[1]), pk2(d3[2], d3[3])};               \
            BOUT[1][nb] = __builtin_bit_cast(bf16x8, u1);                    \
        }                                                                    \
    }

// ---------------- K1: 2 chunks per wave, depth-2 pipeline -------------------
__global__ __launch_bounds__(256, 2) void k_chunks(
    const int* __restrict__ x, const float* __restrict__ lambdas,
    const float* __restrict__ logT, short* __restrict__ M1,
    double* __restrict__ S1) {
    __shared__ short rm[4][64 * RMP];
    __shared__ float pes[4][2][4][64];   // 4-slot ring, 2 chains, 4 waves
    __shared__ int4 xs[4][128];          // 64 rows x 2 int4 per wave
    __shared__ float lgt[20];
    __shared__ double Sw[4];
    const int tid = threadIdx.x;
    const int l = tid & 63, w = tid >> 6;
    const int li = l & 15, q = l >> 4;
    if (tid < 20) lgt[tid] = c_lg[tid];

    const int c0 = (blockIdx.x * 4 + w) * 2;
    const int t0a = 1 + c0 * CHUNK;
    const int t0b = t0a + CHUNK;
    const int lenB = min(CHUNK, TT - t0b);

    // stage 64 x rows (2KB) coalesced: lane l -> slots l and l+64
    {
        int r0 = l >> 1, h = l & 1;
        int tr0 = t0a + r0;
        tr0 = tr0 > TT - 1 ? TT - 1 : tr0;
        xs[w][l] = *(const int4*)(x + (size_t)tr0 * MD + h * 4);
        int tr1 = t0a + 32 + r0;
        tr1 = tr1 > TT - 1 ? TT - 1 : tr1;
        xs[w][l + 64] = *(const int4*)(x + (size_t)tr1 * MD + h * 4);
    }

    float ll[8];
    float lamsum = 0.f;
#pragma unroll
    for (int m = 0; m < 8; ++m) {
        float lam = lambdas[l * 8 + m];
        ll[m] = __logf(lam);
        lamsum += lam;
    }

    // constant A-frags of T (shared by both chunks)
    bf16x8 TA[4][2];
#pragma unroll
    for (int mb = 0; mb < 4; ++mb)
#pragma unroll
        for (int kf = 0; kf < 2; ++kf) {
            const float* tp = logT + (16 * mb + li) * 64 + 32 * kf + 4 * q;
            float4 v0 = *(const float4*)tp;
            float4 v1 = *(const float4*)(tp + 16);
            bf16x8 a;
            a[0] = (__bf16)__expf(v0.x);
            a[1] = (__bf16)__expf(v0.y);
            a[2] = (__bf16)__expf(v0.z);
            a[3] = (__bf16)__expf(v0.w);
            a[4] = (__bf16)__expf(v1.x);
            a[5] = (__bf16)__expf(v1.y);
            a[6] = (__bf16)__expf(v1.z);
            a[7] = (__bf16)__expf(v1.w);
            TA[mb][kf] = a;
        }

    bf16x8 B0a[2][4], B1a[2][4], B0b[2][4], B1b[2][4];
    identity_B(B0a, li, q);
    identity_B(B0b, li, q);
    __syncthreads();  // lgt + xs visible

    double Sa = 0.0, Sb = 0.0;
    float nA_a = 1.0f, nA_b = 1.0f;          // 2-lag nrm (even steps)
    float gE0a, gE1a, gO0a, gO1a;            // gs rings (even/odd, 2-deep)
    float gE0b, gE1b, gO0b, gO1b;
    {
        float pe_;
        emis_ng(xs[w][0], xs[w][1], ll, lamsum, pe_, gE0a);
        pes[0][0][w][l] = pe_;
        emis_ng(xs[w][2], xs[w][3], ll, lamsum, pe_, gO0a);
        pes[1][0][w][l] = pe_;
        emis_ng(xs[w][64], xs[w][65], ll, lamsum, pe_, gE0b);
        pes[0][1][w][l] = pe_;
        emis_ng(xs[w][66], xs[w][67], ll, lamsum, pe_, gO0b);
        pes[1][1][w][l] = pe_;
    }

    int s = 0;
#pragma unroll 1
    for (int p = 0; p < 7; ++p) {  // 28 steps
        STEPE(B0a, B1a, nA_a, gE0a, gE1a, Sa, 0);
        STEPE(B0b, B1b, nA_b, gE0b, gE1b, Sb, 1);
        ++s;
        STEPO(B1a, B0a, gO0a, gO1a, Sa, 0);
        STEPO(B1b, B0b, gO0b, gO1b, Sb, 1);
        ++s;
        STEPE(B0a, B1a, nA_a, gE1a, gE0a, Sa, 0);
        STEPE(B0b, B1b, nA_b, gE1b, gE0b, Sb, 1);
        ++s;
        STEPO(B1a, B0a, gO1a, gO0a, Sa, 0);
        STEPO(B1b, B0b, gO1b, gO0b, Sb, 1);
        ++s;
    }
    // tail: steps 28..31 (ring names as at body start)
    STEPE(B0a, B1a, nA_a, gE0a, gE1a, Sa, 0);
    STEPE(B0b, B1b, nA_b, gE0b, gE1b, Sb, 1);
    ++s;
    STEPO(B1a, B0a, gO0a, gO1a, Sa, 0);
    STEPO(B1b, B0b, gO0b, gO1b, Sb, 1);
    ++s;
    STEPE(B0a, B1a, nA_a, gE1a, gE0a, Sa, 0);
    STEPE(B0b, B1b, nA_b, gE1b, gE0b, Sb, 1);
    ++s;
    STEPO(B1a, B0a, gO1a, gO0a, Sa, 0);
    if (lenB == CHUNK) {
        STEPO(B1b, B0b, gO1b, gO0b, Sb, 1);
    } else {
#pragma unroll
        for (int kf = 0; kf < 2; ++kf)
#pragma unroll
            for (int nb = 0; nb < 4; ++nb) B0b[kf][nb] = B1b[kf][nb];
    }

    // hoisted lgamma over both chunks (64 staged rows, from LDS)
    {
        const int lenTot = CHUNK + lenB;
        float lt = 0.f;
        if (l < lenTot) {
            int4 a = xs[w][2 * l], b = xs[w][2 * l + 1];
            lt = lgt[a.x] + lgt[a.y] + lgt[a.z] + lgt[a.w] + lgt[b.x] +
                 lgt[b.y] + lgt[b.z] + lgt[b.w];
        }
#pragma unroll
        for (int m = 1; m <= 32; m <<= 1) lt += __shfl_xor(lt, m, 64);
        Sa -= (double)lt;
    }

    // ---- intra-wave pair product: Mpair = M_B * M_A ----
    state_to_rm(&rm[w][0], B0b, li, q);
    {
        bf16x8 Ap[4][2];
        load_afrags(&rm[w][0], li, q, Ap);
        float pm = leftmul(Ap, B0a);
        Sa += Sb + (double)__logf(pm);
    }

    // ---- cross-wave combine: product = P3*P2*P1*P0 ----
    __syncthreads();
    if (w) state_to_rm(&rm[w][0], B0a, li, q);
    if (l == 0) Sw[w] = Sa;
    __syncthreads();
    if (w == 0) {
        double S = Sa;
#pragma unroll 1
        for (int j = 1; j < 4; ++j) {
            bf16x8 A[4][2];
            load_afrags(&rm[j][0], li, q, A);
            float pm = leftmul(A, B0a);
            S += Sw[j] + (double)__logf(pm);
        }
        dump_rm_g(M1 + (size_t)blockIdx.x * 4096, B0a, li, q);
        if (l == 0) S1[blockIdx.x] = S;
    }
}

// ---------------- K2: fold 512 -> 32 ----------------------------------------
__global__ __launch_bounds__(256, 1) void k_combine(
    const short* __restrict__ M1, const double* __restrict__ S1,
    short* __restrict__ M2, double* __restrict__ S2) {
    __shared__ short rm[4][64 * RMP];
    __shared__ double Sw[4];
    const int tid = threadIdx.x;
    const int l = tid & 63, w = tid >> 6;
    const int li = l & 15, q = l >> 4;
    const int base = (blockIdx.x * 4 + w) * 4;

    bf16x8 B[2][4];
    identity_B(B, li, q);
    double S = 0.0;
    bf16x8 Aa[4][2], Ab[4][2];
    load_afrags_g(M1 + (size_t)base * 4096, li, q, Aa);
    load_afrags_g(M1 + (size_t)(base + 1) * 4096, li, q, Ab);
    float pm = leftmul(Aa, B);
    S += S1[base] + (double)__logf(pm);
    load_afrags_g(M1 + (size_t)(base + 2) * 4096, li, q, Aa);
    pm = leftmul(Ab, B);
    S += S1[base + 1] + (double)__logf(pm);
    load_afrags_g(M1 + (size_t)(base + 3) * 4096, li, q, Ab);
    pm = leftmul(Aa, B);
    S += S1[base + 2] + (double)__logf(pm);
    pm = leftmul(Ab, B);
    S += S1[base + 3] + (double)__logf(pm);

    if (w) state_to_rm(&rm[w][0], B, li, q);
    if (l == 0) Sw[w] = S;
    __syncthreads();
    if (w == 0) {
#pragma unroll 1
        for (int j = 1; j < 4; ++j) {
            bf16x8 A[4][2];
            load_afrags(&rm[j][0], li, q, A);
            float pmj = leftmul(A, B);
            S += Sw[j] + (double)__logf(pmj);
        }
        dump_rm_g(M2 + (size_t)blockIdx.x * 4096, B, li, q);
        if (l == 0) S2[blockIdx.x] = S;
    }
}

// ---------------- K3: fold 32 -> 1, alpha0, final LSE ------------------------
__global__ __launch_bounds__(256, 1) void k_final(
    const int* __restrict__ x, const float* __restrict__ lambdas,
    const float* __restrict__ prior, const short* __restrict__ M2,
    const double* __restrict__ S2, float* __restrict__ out) {
    __shared__ short rm[4][64 * RMP];
    __shared__ double Sw[4];
    __shared__ float lgt[20];
    const int tid = threadIdx.x;
    const int l = tid & 63, w = tid >> 6;
    const int li = l & 15, q = l >> 4;
    if (tid < 20) lgt[tid] = c_lg[tid];
    __syncthreads();

    const int base = w * 8;
    bf16x8 B[2][4];
    identity_B(B, li, q);
    double S = 0.0;
    bf16x8 Aa[4][2], Ab[4][2];
    load_afrags_g(M2 + (size_t)base * 4096, li, q, Aa);
#pragma unroll
    for (int j = 0; j < 8; j += 2) {
        load_afrags_g(M2 + (size_t)(base + j + 1) * 4096, li, q, Ab);
        float pm = leftmul(Aa, B);
        S += S2[base + j] + (double)__logf(pm);
        if (j + 2 < 8)
            load_afrags_g(M2 + (size_t)(base + j + 2) * 4096, li, q, Aa);
        pm = leftmul(Ab, B);
        S += S2[base + j + 1] + (double)__logf(pm);
    }

    if (w) state_to_rm(&rm[w][0], B, li, q);
    if (l == 0) Sw[w] = S;
    __syncthreads();
    if (w == 0) {
#pragma unroll 1
        for (int j = 1; j < 4; ++j) {
            bf16x8 A[4][2];
            load_afrags(&rm[j][0], li, q, A);
            float pm = leftmul(A, B);
            S += Sw[j] + (double)__logf(pm);
        }
        // finalize: alpha0 = em_0 * exp(prior); total = 1^T B alpha0
        float ll[8];
        float lamsum = 0.f;
#pragma unroll
        for (int m = 0; m < 8; ++m) {
            float lam = lambdas[l * 8 + m];
            ll[m] = __logf(lam);
            lamsum += lam;
        }
        int4 xa = *(const int4*)(x);
        int4 xb = *(const int4*)(x + 4);
        float pe0, gs0;
        emis(xa, xb, ll, lamsum, lgt, pe0, gs0);
        S += (double)gs0;
        float a0 = pe0 * __expf(prior[l]);

        float av[4];
#pragma unroll
        for (int nb = 0; nb < 4; ++nb) av[nb] = __shfl(a0, 16 * nb + li, 64);

        float acc = 0.f;
#pragma unroll
        for (int kf = 0; kf < 2; ++kf)
#pragma unroll
            for (int nb = 0; nb < 4; ++nb) {
                u32x4 u = __builtin_bit_cast(u32x4, B[kf][nb]);
#pragma unroll
                for (int e = 0; e < 4; ++e) {
                    float flo = __builtin_bit_cast(float, u[e] << 16);
                    float fhi = __builtin_bit_cast(float, u[e] & 0xFFFF0000u);
                    acc = fmaf(flo + fhi, av[nb], acc);
                }
            }
#pragma unroll
        for (int m = 1; m <= 32; m <<= 1) acc += __shfl_xor(acc, m, 64);
        if (l == 0) out[0] = (float)(S + (double)__logf(acc));
    }
}

extern "C" void kernel_launch(void* const* d_in, const int* in_sizes, int n_in,
                              void* d_out, int out_size, void* d_ws,
                              size_t ws_size, hipStream_t stream) {
    const int* x = (const int*)d_in[0];
    const float* lambdas = (const float*)d_in[1];
    const float* logT = (const float*)d_in[2];
    const float* prior = (const float*)d_in[3];
    float* out = (float*)d_out;
    char* ws = (char*)d_ws;
    // ws layout (~4.46 MB): M1 512*8KB, S1 512*8B, M2 32*8KB, S2 32*8B
    short* M1 = (short*)ws;
    double* S1 = (double*)(ws + 4194304);
    short* M2 = (short*)(ws + 4198400);
    double* S2 = (double*)(ws + 4460544);

    k_chunks<<<512, 256, 0, stream>>>(x, lambdas, logT, M1, S1);
    k_combine<<<32, 256, 0, stream>>>(M1, S1, M2, S2);
    k_final<<<1, 256, 0, stream>>>(x, lambdas, prior, M2, S2, out);
}